// Round 7
// baseline (844.445 us; speedup 1.0000x reference)
//
#include <hip/hip_runtime.h>
#include <math.h>

// Swin block: B=8, C=256, H=W=128, WS=8, SS=4, NH=8, dh=32
// Single fused per-window kernel: LN1 -> QKV -> attn -> out-proj(+x residual)
// -> LN2 -> MLP -> (+win2 residual) -> NCHW scatter. win2 never leaves the block.

#define LDH 264   // bf16 row stride for [64][256] tiles
#define LDS_S 40  // bf16 row stride for per-wave q/k slots [64][40]
#define LDVT 72   // bf16 row stride for vT [32][72] (>=64: no aliasing!)
#define LDM 136   // bf16 row stride for m chunk [64][128]

typedef __attribute__((ext_vector_type(8))) short bf16x8;
typedef __attribute__((ext_vector_type(4))) short bf16x4;
typedef __attribute__((ext_vector_type(4))) float f32x4;

static __device__ __forceinline__ float bf2f(short s){
  union { unsigned u; float f; } cv;
  cv.u = ((unsigned)(unsigned short)s) << 16;
  return cv.f;
}
static __device__ __forceinline__ short f2bf(float f){
  union { float f; unsigned u; } cv; cv.f = f;
  unsigned r = (cv.u + 0x7FFFu + ((cv.u >> 16) & 1u)) >> 16;  // RNE
  return (short)r;
}
static __device__ __forceinline__ float gelu_f(float x){
  return 0.5f * x * (1.0f + erff(x * 0.7071067811865475f));
}

// ---------------- K0: merged fp32 -> bf16 weight convert ----------------
__global__ void wconv_kernel(const float* __restrict__ inw, const float* __restrict__ outw,
                             const float* __restrict__ w1f, const float* __restrict__ w2f,
                             short* __restrict__ dst){
  int i = blockIdx.x * 256 + threadIdx.x;   // grid covers exactly 786432
  const float* s; int off;
  if (i < 196608){ s = inw;  off = 0; }
  else if (i < 262144){ s = outw; off = 196608; }
  else if (i < 524288){ s = w1f;  off = 262144; }
  else { s = w2f; off = 524288; }
  dst[i] = f2bf(s[i - off]);
}

// [64x256] @ [256 x 32] GEMM helper: A from sh (token rows), B rows wrowbase.. of w
__device__ __forceinline__ void gemm_h_w32(const short* sh,
                                           const short* __restrict__ w, int wrowbase,
                                           int rowa, int kg, f32x4 acc[4][2]){
  #pragma unroll
  for (int kt = 0; kt < 8; ++kt){
    bf16x8 av[4], bw[2];
    #pragma unroll
    for (int mt=0;mt<4;++mt)
      av[mt] = *(const bf16x8*)&sh[(mt*16+rowa)*LDH + kt*32 + kg*8];
    #pragma unroll
    for (int nt=0;nt<2;++nt)
      bw[nt] = *(const bf16x8*)&w[(wrowbase + nt*16 + rowa)*256 + kt*32 + kg*8];
    #pragma unroll
    for (int mt=0;mt<4;++mt)
      #pragma unroll
      for (int nt=0;nt<2;++nt)
        acc[mt][nt] = __builtin_amdgcn_mfma_f32_16x16x32_bf16(av[mt], bw[nt], acc[mt][nt], 0, 0, 0);
  }
}

// GEMM1(chunk): acc1[rt][ct] += w1-rows x Y-tokens (swapped, D[hid][tok])
__device__ __forceinline__ void mlp_gemm1(const short* __restrict__ w1, const short* Y,
                                          int chk, int wv, int rowa, int kg,
                                          f32x4 acc1[2][4]){
  #pragma unroll
  for (int kt=0;kt<8;++kt){
    bf16x8 aw[2], bh[4];
    #pragma unroll
    for (int rt=0;rt<2;++rt)
      aw[rt] = *(const bf16x8*)&w1[(chk*128 + wv*32 + rt*16 + rowa)*256 + kt*32 + kg*8];
    #pragma unroll
    for (int ct=0;ct<4;++ct)
      bh[ct] = *(const bf16x8*)&Y[(ct*16+rowa)*LDH + kt*32 + kg*8];
    #pragma unroll
    for (int rt=0;rt<2;++rt)
      #pragma unroll
      for (int ct=0;ct<4;++ct)
        acc1[rt][ct] = __builtin_amdgcn_mfma_f32_16x16x32_bf16(aw[rt], bh[ct], acc1[rt][ct], 0, 0, 0);
  }
}

__device__ __forceinline__ void mlp_gelu_store(short* M, const float* __restrict__ b1,
                                               int chk, int wv, int rowa, int kg,
                                               const f32x4 acc1[2][4]){
  #pragma unroll
  for (int rt=0;rt<2;++rt){
    const int hidb = wv*32 + rt*16 + kg*4;
    const f32x4 b1v = *(const f32x4*)&b1[chk*128 + hidb];
    #pragma unroll
    for (int ct=0;ct<4;++ct){
      bf16x4 st;
      #pragma unroll
      for (int i=0;i<4;++i)
        st[i] = f2bf(gelu_f(acc1[rt][ct][i] + b1v[i]));
      *(bf16x4*)&M[(ct*16 + rowa)*LDM + hidb] = st;
    }
  }
}

// GEMM2(chunk) SWAPPED: acc2[c0][t0] += w2-ch-rows x M-tokens
__device__ __forceinline__ void mlp_gemm2(const short* M, const short* __restrict__ w2,
                                          int chk, int wv, int rowa, int kg,
                                          f32x4 acc2[4][4]){
  #pragma unroll
  for (int kt2=0;kt2<4;++kt2){
    bf16x8 aw2[4], bm[4];
    #pragma unroll
    for (int c0=0;c0<4;++c0)
      aw2[c0] = *(const bf16x8*)&w2[(wv*64 + c0*16+rowa)*1024 + chk*128 + kt2*32 + kg*8];
    #pragma unroll
    for (int t0=0;t0<4;++t0)
      bm[t0] = *(const bf16x8*)&M[(t0*16+rowa)*LDM + kt2*32 + kg*8];
    #pragma unroll
    for (int c0=0;c0<4;++c0)
      #pragma unroll
      for (int t0=0;t0<4;++t0)
        acc2[c0][t0] = __builtin_amdgcn_mfma_f32_16x16x32_bf16(aw2[c0], bm[t0], acc2[c0][t0], 0, 0, 0);
  }
}

// ---------------- fused per-window kernel ----------------
// LDS (74752 B -> 2 blocks/CU):
//   [0,     33792)  sh: h -> o -> win2/Y(h2)  bf16 [64][264]
//   [33792, 74752)  slots: 4 waves x (slotA[64][40] q/P, slotB k[64][40]/vT[32][72])
//                   also hosts red scratch (phases A,D) and M [64][136] (phase E)
#define KF_OFF_WV  33792
#define KF_SMEM    74752

__global__ __launch_bounds__(256, 2)
void swin_fused_kernel(const float* __restrict__ x,
                       const float* __restrict__ ln1w, const float* __restrict__ ln1b,
                       const float* __restrict__ inb,  const float* __restrict__ outb,
                       const float* __restrict__ ln2w, const float* __restrict__ ln2b,
                       const float* __restrict__ b1,   const float* __restrict__ b2,
                       const short* __restrict__ wqkv, const short* __restrict__ wout,
                       const short* __restrict__ w1,   const short* __restrict__ w2,
                       float* __restrict__ out)
{
  __shared__ char smem[KF_SMEM];
  short* sh     = (short*)smem;
  short* slots  = (short*)(smem + KF_OFF_WV);
  float* red_s  = (float*)(smem + KF_OFF_WV);   // transient (phases A, D)
  float* red_q2 = red_s + 256;

  const int tid = threadIdx.x;
  const int wv  = tid >> 6;
  const int ln  = tid & 63;
  const int rowa = ln & 15;
  const int kg   = ln >> 4;

  short* slotA = slots + wv*5120;   // [64][40] shorts
  short* slotB = slotA + 2560;      // k [64][40] -> vT [32][72]
  short* M     = slots;             // [64][136] (phase E)

  const int wi = blockIdx.x;
  const int b  = wi >> 8;
  const int wh = (wi >> 4) & 15;
  const int ww = wi & 15;

  const int hh = (wh*8 + (ln >> 3) + 4) & 127;   // roll(-4)
  const int wc = (ww*8 + (ln & 7) + 4) & 127;
  const int offhw = hh*128 + wc;
  const int xbase = b << 22;

  // ================= phase A: LN1 -> h in sh =================
  {
    const int cbeg = wv*64;
    float vals[64];
    float s = 0.f, sq = 0.f;
    #pragma unroll
    for (int j = 0; j < 64; ++j){
      float v = x[xbase + ((cbeg + j) << 14) + offhw];
      vals[j] = v; s += v; sq += v*v;
    }
    red_s[cbeg + ln]  = s;
    red_q2[cbeg + ln] = sq;
    __syncthreads();
    float sum = red_s[ln] + red_s[64+ln] + red_s[128+ln] + red_s[192+ln];
    float ssq = red_q2[ln] + red_q2[64+ln] + red_q2[128+ln] + red_q2[192+ln];
    float mean = sum * 0.00390625f;
    float var  = ssq * 0.00390625f - mean*mean;
    float rstd = rsqrtf(var + 1e-5f);
    #pragma unroll
    for (int j = 0; j < 64; ++j){
      const int c = cbeg + j;
      sh[ln*LDH + c] = f2bf((vals[j] - mean) * rstd * ln1w[c] + ln1b[c]);
    }
  }
  __syncthreads();

  // ================= phase B: per-wave attention (heads 2wv, 2wv+1) =================
  const float scale = 0.1767766952966369f;  // 1/sqrt(32)
  f32x4 oacc[4][4];
  #pragma unroll
  for (int mt=0;mt<4;++mt)
    #pragma unroll
    for (int j=0;j<4;++j)
      oacc[mt][j] = (f32x4){0.f,0.f,0.f,0.f};

  #pragma unroll
  for (int hd = 0; hd < 2; ++hd){
    const int hc = (2*wv + hd) * 32;

    // q -> slotA
    {
      f32x4 accq[4][2];
      #pragma unroll
      for (int mt=0;mt<4;++mt){ accq[mt][0]=(f32x4){0,0,0,0}; accq[mt][1]=(f32x4){0,0,0,0}; }
      gemm_h_w32(sh, wqkv, 0*256 + hc, rowa, kg, accq);
      #pragma unroll
      for (int nt=0;nt<2;++nt){
        const float bias = inb[hc + nt*16 + rowa];
        #pragma unroll
        for (int mt=0;mt<4;++mt)
          #pragma unroll
          for (int i=0;i<4;++i)
            slotA[(mt*16 + kg*4 + i)*LDS_S + nt*16 + rowa] = f2bf(accq[mt][nt][i] + bias);
      }
    }
    // k -> slotB
    {
      f32x4 acck[4][2];
      #pragma unroll
      for (int mt=0;mt<4;++mt){ acck[mt][0]=(f32x4){0,0,0,0}; acck[mt][1]=(f32x4){0,0,0,0}; }
      gemm_h_w32(sh, wqkv, 1*256 + hc, rowa, kg, acck);
      #pragma unroll
      for (int nt=0;nt<2;++nt){
        const float bias = inb[256 + hc + nt*16 + rowa];
        #pragma unroll
        for (int mt=0;mt<4;++mt)
          #pragma unroll
          for (int i=0;i<4;++i)
            slotB[(mt*16 + kg*4 + i)*LDS_S + nt*16 + rowa] = f2bf(acck[mt][nt][i] + bias);
      }
    }

    // S = q @ k^T
    f32x4 sacc[4][4];
    #pragma unroll
    for (int mt=0;mt<4;++mt)
      #pragma unroll
      for (int nt=0;nt<4;++nt)
        sacc[mt][nt] = (f32x4){0.f,0.f,0.f,0.f};
    {
      bf16x8 aq[4], bk[4];
      #pragma unroll
      for (int mt=0;mt<4;++mt)
        aq[mt] = *(const bf16x8*)&slotA[(mt*16+rowa)*LDS_S + kg*8];
      #pragma unroll
      for (int nt=0;nt<4;++nt)
        bk[nt] = *(const bf16x8*)&slotB[(nt*16+rowa)*LDS_S + kg*8];
      __builtin_amdgcn_s_setprio(1);
      #pragma unroll
      for (int mt=0;mt<4;++mt)
        #pragma unroll
        for (int nt=0;nt<4;++nt)
          sacc[mt][nt] = __builtin_amdgcn_mfma_f32_16x16x32_bf16(aq[mt], bk[nt], sacc[mt][nt], 0, 0, 0);
      __builtin_amdgcn_s_setprio(0);
    }

    // v -> vT [32][72] in slotB (k consumed; stride 72 >= 64 -> no aliasing)
    {
      f32x4 accv[4][2];
      #pragma unroll
      for (int mt=0;mt<4;++mt){ accv[mt][0]=(f32x4){0,0,0,0}; accv[mt][1]=(f32x4){0,0,0,0}; }
      gemm_h_w32(sh, wqkv, 2*256 + hc, rowa, kg, accv);
      #pragma unroll
      for (int nt=0;nt<2;++nt){
        const float bias = inb[512 + hc + nt*16 + rowa];
        #pragma unroll
        for (int mt=0;mt<4;++mt)
          #pragma unroll
          for (int i=0;i<4;++i)
            slotB[(nt*16 + rowa)*LDVT + mt*16 + kg*4 + i] = f2bf(accv[mt][nt][i] + bias);  // [ch][tok]
      }
    }

    // softmax
    #pragma unroll
    for (int mt=0;mt<4;++mt){
      #pragma unroll
      for (int i=0;i<4;++i){
        float v0 = sacc[mt][0][i]*scale;
        float v1 = sacc[mt][1][i]*scale;
        float v2 = sacc[mt][2][i]*scale;
        float v3 = sacc[mt][3][i]*scale;
        float mx = fmaxf(fmaxf(v0,v1), fmaxf(v2,v3));
        #pragma unroll
        for (int d=1; d<16; d<<=1) mx = fmaxf(mx, __shfl_xor(mx, d, 64));
        v0 = __expf(v0-mx); v1 = __expf(v1-mx); v2 = __expf(v2-mx); v3 = __expf(v3-mx);
        float sm = v0+v1+v2+v3;
        #pragma unroll
        for (int d=1; d<16; d<<=1) sm += __shfl_xor(sm, d, 64);
        const float inv = 1.f / sm;
        sacc[mt][0][i] = v0*inv; sacc[mt][1][i] = v1*inv;
        sacc[mt][2][i] = v2*inv; sacc[mt][3][i] = v3*inv;
      }
    }

    // PV in two kv-chunks of 32, P through slotA
    #pragma unroll
    for (int ck=0; ck<2; ++ck){
      #pragma unroll
      for (int ntl=0; ntl<2; ++ntl)
        #pragma unroll
        for (int mt=0;mt<4;++mt)
          #pragma unroll
          for (int i=0;i<4;++i)
            slotA[(mt*16 + kg*4 + i)*LDS_S + ntl*16 + rowa] = f2bf(sacc[mt][2*ck+ntl][i]);
      bf16x8 ap[4], bv[2];
      #pragma unroll
      for (int mt=0;mt<4;++mt)
        ap[mt] = *(const bf16x8*)&slotA[(mt*16+rowa)*LDS_S + kg*8];
      #pragma unroll
      for (int nt=0;nt<2;++nt)
        bv[nt] = *(const bf16x8*)&slotB[(nt*16+rowa)*LDVT + ck*32 + kg*8];
      __builtin_amdgcn_s_setprio(1);
      #pragma unroll
      for (int mt=0;mt<4;++mt)
        #pragma unroll
        for (int nt=0;nt<2;++nt)
          oacc[mt][hd*2+nt] = __builtin_amdgcn_mfma_f32_16x16x32_bf16(ap[mt], bv[nt], oacc[mt][hd*2+nt], 0, 0, 0);
      __builtin_amdgcn_s_setprio(0);
    }
  }

  __syncthreads();   // all waves done reading h -> sh becomes o

  #pragma unroll
  for (int j=0;j<4;++j){
    const int col = wv*64 + j*16 + rowa;
    #pragma unroll
    for (int mt=0;mt<4;++mt)
      #pragma unroll
      for (int i=0;i<4;++i)
        sh[(mt*16 + kg*4 + i)*LDH + col] = f2bf(oacc[mt][j][i]);
  }
  __syncthreads();

  // ================= phase C: out-proj SWAPPED -> D'[ch][tok]; win2 to sh + regs ==========
  unsigned rpack[4][4][2];   // win2 bf16 pairs (residual for phase F), static-indexed
  {
    f32x4 acc[4][4];   // [c0(ch)][t0(tok)]
    #pragma unroll
    for (int c0=0;c0<4;++c0)
      #pragma unroll
      for (int t0=0;t0<4;++t0)
        acc[c0][t0] = (f32x4){0.f,0.f,0.f,0.f};
    for (int kt=0; kt<8; ++kt){
      bf16x8 aw[4], bo[4];
      #pragma unroll
      for (int c0=0;c0<4;++c0)
        aw[c0] = *(const bf16x8*)&wout[(wv*64 + c0*16 + rowa)*256 + kt*32 + kg*8];
      #pragma unroll
      for (int t0=0;t0<4;++t0)
        bo[t0] = *(const bf16x8*)&sh[(t0*16+rowa)*LDH + kt*32 + kg*8];
      #pragma unroll
      for (int c0=0;c0<4;++c0)
        #pragma unroll
        for (int t0=0;t0<4;++t0)
          acc[c0][t0] = __builtin_amdgcn_mfma_f32_16x16x32_bf16(aw[c0], bo[t0], acc[c0][t0], 0, 0, 0);
    }
    __syncthreads();   // all o reads done before win2 overwrites sh

    #pragma unroll
    for (int c0=0;c0<4;++c0){
      #pragma unroll
      for (int t0=0;t0<4;++t0){
        const int tok = t0*16 + rowa;
        const int r = tok >> 3, cw = tok & 7;
        const int hh2 = (wh*8 + r + 4) & 127;
        const int wc2 = (ww*8 + cw + 4) & 127;
        bf16x4 st;
        unsigned p0 = 0, p1 = 0;
        #pragma unroll
        for (int i=0;i<4;++i){
          const int ch = wv*64 + c0*16 + kg*4 + i;
          const float v = acc[c0][t0][i] + outb[ch] + x[xbase + (ch << 14) + hh2*128 + wc2];
          const unsigned us = (unsigned)(unsigned short)f2bf(v);
          st[i] = (short)us;
          if (i < 2) p0 |= us << (16*i); else p1 |= us << (16*(i-2));
        }
        rpack[c0][t0][0] = p0; rpack[c0][t0][1] = p1;
        *(bf16x4*)&sh[tok*LDH + wv*64 + c0*16 + kg*4] = st;   // win2 [tok][ch]
      }
    }
  }
  __syncthreads();   // win2 complete in sh

  // ================= phase D: LN2 (in-place: sh win2 -> h2) =================
  {
    float vals[64];
    float s = 0.f, sq = 0.f;
    const int cbeg = wv*64;
    #pragma unroll
    for (int j=0;j<64;++j){
      float v = bf2f(sh[ln*LDH + cbeg + j]);
      vals[j] = v; s += v; sq += v*v;
    }
    red_s[cbeg + ln]  = s;
    red_q2[cbeg + ln] = sq;
    __syncthreads();
    float sum = red_s[ln] + red_s[64+ln] + red_s[128+ln] + red_s[192+ln];
    float ssq = red_q2[ln] + red_q2[64+ln] + red_q2[128+ln] + red_q2[192+ln];
    float mean = sum * 0.00390625f;
    float var  = ssq * 0.00390625f - mean*mean;
    float rstd = rsqrtf(var + 1e-5f);
    #pragma unroll
    for (int q=0;q<8;++q){
      bf16x8 pk;
      #pragma unroll
      for (int e=0;e<8;++e){
        const int c = cbeg + q*8 + e;
        pk[e] = f2bf((vals[q*8+e] - mean) * rstd * ln2w[c] + ln2b[c]);
      }
      *(bf16x8*)&sh[ln*LDH + cbeg + q*8] = pk;
    }
  }
  __syncthreads();   // h2 ready (red consumed; slots area becomes M)

  // ================= phase E: pipelined MLP =================
  f32x4 acc2[4][4];
  #pragma unroll
  for (int c0=0;c0<4;++c0)
    #pragma unroll
    for (int t0=0;t0<4;++t0)
      acc2[c0][t0] = (f32x4){0.f,0.f,0.f,0.f};

  {
    f32x4 acc1[2][4];
    #pragma unroll
    for (int rt=0;rt<2;++rt)
      #pragma unroll
      for (int ct=0;ct<4;++ct)
        acc1[rt][ct] = (f32x4){0.f,0.f,0.f,0.f};
    mlp_gemm1(w1, sh, 0, wv, rowa, kg, acc1);
    mlp_gelu_store(M, b1, 0, wv, rowa, kg, acc1);
  }
  __syncthreads();   // M(0) ready

  #pragma unroll
  for (int c = 0; c < 8; ++c){
    if (c < 7){
      f32x4 acc1n[2][4];
      #pragma unroll
      for (int rt=0;rt<2;++rt)
        #pragma unroll
        for (int ct=0;ct<4;++ct)
          acc1n[rt][ct] = (f32x4){0.f,0.f,0.f,0.f};
      mlp_gemm1(w1, sh, c+1, wv, rowa, kg, acc1n);
      mlp_gemm2(M, w2, c, wv, rowa, kg, acc2);
      __syncthreads();   // all M(c) reads done
      mlp_gelu_store(M, b1, c+1, wv, rowa, kg, acc1n);
      __syncthreads();   // M(c+1) ready
    } else {
      mlp_gemm2(M, w2, c, wv, rowa, kg, acc2);
    }
  }

  // ================= phase F: epilogue (+b2 + win2 residual from rpack) =================
  #pragma unroll
  for (int c0=0;c0<4;++c0){
    #pragma unroll
    for (int i=0;i<4;++i){
      const int ch = wv*64 + c0*16 + kg*4 + i;
      const float bias = b2[ch];
      #pragma unroll
      for (int t0=0;t0<4;++t0){
        const int tok = t0*16 + rowa;
        const unsigned pw = rpack[c0][t0][i>>1];
        const short rs = (short)((pw >> (16*(i&1))) & 0xffffu);
        float v = acc2[c0][t0][i] + bias + bf2f(rs);
        const int r = tok >> 3, cw = tok & 7;
        const int hh2 = (wh*8 + r + 4) & 127;
        const int wc2 = (ww*8 + cw + 4) & 127;
        out[(((b<<8) + ch) << 14) + hh2*128 + wc2] = v;
      }
    }
  }
}

// ---------------- launch ----------------
extern "C" void kernel_launch(void* const* d_in, const int* in_sizes, int n_in,
                              void* d_out, int out_size, void* d_ws, size_t ws_size,
                              hipStream_t stream) {
  (void)in_sizes; (void)n_in; (void)out_size; (void)ws_size;
  const float* x    = (const float*)d_in[0];
  const float* ln1w = (const float*)d_in[1];
  const float* ln1b = (const float*)d_in[2];
  const float* inw  = (const float*)d_in[3];
  const float* inb  = (const float*)d_in[4];
  const float* outw = (const float*)d_in[5];
  const float* outb = (const float*)d_in[6];
  const float* ln2w = (const float*)d_in[7];
  const float* ln2b = (const float*)d_in[8];
  const float* w1f  = (const float*)d_in[9];
  const float* b1   = (const float*)d_in[10];
  const float* w2f  = (const float*)d_in[11];
  const float* b2   = (const float*)d_in[12];
  float* out = (float*)d_out;

  short* ws    = (short*)d_ws;
  short* wqkv  = ws;            // 768*256
  short* wout  = ws + 196608;   // 256*256
  short* w1b   = ws + 262144;   // 1024*256
  short* w2b   = ws + 524288;   // 256*1024

  hipLaunchKernelGGL(wconv_kernel, dim3(3072), dim3(256), 0, stream, inw, outw, w1f, w2f, ws);
  hipLaunchKernelGGL(swin_fused_kernel, dim3(2048), dim3(256), 0, stream,
                     x, ln1w, ln1b, inb, outb, ln2w, ln2b, b1, b2,
                     wqkv, wout, w1b, w2b, out);
}

// Round 8
// 680.356 us; speedup vs baseline: 1.2412x; 1.2412x over previous
//
#include <hip/hip_runtime.h>
#include <math.h>

// Swin block: B=8, C=256, H=W=128, WS=8, SS=4, NH=8, dh=32
// Split kernels; weights repacked into MFMA-fragment order:
//   wf[((tile*KT + kt)*64 + lane)*8 + e] = W[tile*16 + (lane&15)][kt*32 + (lane>>4)*8 + e]
// so each B-frag load is one contiguous 1KB wave read.

#define LDH 264   // bf16 row stride for [64][256] tiles
#define LDS_S 40  // bf16 row stride for per-wave q/k slots [64][40]
#define LDVT 72   // bf16 row stride for vT [32][72] (>=64: no aliasing)
#define LDM 136   // bf16 row stride for m chunk [64][128]

typedef __attribute__((ext_vector_type(8))) short bf16x8;
typedef __attribute__((ext_vector_type(4))) short bf16x4;
typedef __attribute__((ext_vector_type(4))) float f32x4;

#define WF(wf, tile, KT, kt, ln) (*(const bf16x8*)&(wf)[((((tile)*(KT)) + (kt))*64 + (ln))*8])

static __device__ __forceinline__ float bf2f(short s){
  union { unsigned u; float f; } cv;
  cv.u = ((unsigned)(unsigned short)s) << 16;
  return cv.f;
}
static __device__ __forceinline__ short f2bf(float f){
  union { float f; unsigned u; } cv; cv.f = f;
  unsigned r = (cv.u + 0x7FFFu + ((cv.u >> 16) & 1u)) >> 16;  // RNE
  return (short)r;
}
static __device__ __forceinline__ float gelu_f(float x){
  return 0.5f * x * (1.0f + erff(x * 0.7071067811865475f));
}

// ---------------- K0: fp32 -> bf16 fragment-order repack ----------------
__global__ void wpack_kernel(const float* __restrict__ src, short* __restrict__ dst,
                             int K){
  const int t8 = blockIdx.x * 256 + threadIdx.x;   // one thread per 8 elements
  const int e0 = t8 * 8;
  const int l   = (e0 >> 3) & 63;
  const int blk = e0 >> 9;          // tile*KT + kt
  const int KT  = K >> 5;
  const int kt   = blk % KT;
  const int tile = blk / KT;
  const int row = tile*16 + (l & 15);
  const int kb  = kt*32 + (l >> 4)*8;
  const float* s = src + row*K + kb;
  bf16x8 o;
  #pragma unroll
  for (int e=0;e<8;++e) o[e] = f2bf(s[e]);
  *(bf16x8*)&dst[e0] = o;
}

// ---------------- kernel 1: LN1 + QKV + attention + out-proj(swapped) -> win2T ----------------
#define K1_OFF_WV  33792
#define K1_OFF_RED 74752
#define K1_SMEM    76800

__global__ __launch_bounds__(256, 2)
void swin_attn_kernel(const float* __restrict__ x,
                      const float* __restrict__ ln1w, const float* __restrict__ ln1b,
                      const float* __restrict__ inb,  const float* __restrict__ outb,
                      const short* __restrict__ wqkv, const short* __restrict__ wout,
                      short* __restrict__ win2T)
{
  __shared__ char smem[K1_SMEM];
  short* sh_h   = (short*)smem;
  float* red_s  = (float*)(smem + K1_OFF_RED);
  float* red_q2 = red_s + 256;

  const int tid = threadIdx.x;
  const int wv  = tid >> 6;
  const int ln  = tid & 63;
  const int rowa = ln & 15;
  const int kg   = ln >> 4;

  short* slotA = (short*)(smem + K1_OFF_WV) + wv*5120;  // [64][40]
  short* slotB = slotA + 2560;                          // k[64][40] -> vT[32][72]

  const int wi = blockIdx.x;
  const int b  = wi >> 8;
  const int wh = (wi >> 4) & 15;
  const int ww = wi & 15;

  const int hh = (wh*8 + (ln >> 3) + 4) & 127;   // roll(-4)
  const int wc = (ww*8 + (ln & 7) + 4) & 127;
  const int offhw = hh*128 + wc;
  const int xbase = b << 22;

  // ---- LN1 (values in regs) ----
  {
    const int cbeg = wv*64;
    float vals[64];
    float s = 0.f, sq = 0.f;
    #pragma unroll
    for (int j = 0; j < 64; ++j){
      float v = x[xbase + ((cbeg + j) << 14) + offhw];
      vals[j] = v; s += v; sq += v*v;
    }
    red_s[cbeg + ln]  = s;
    red_q2[cbeg + ln] = sq;
    __syncthreads();
    float sum = red_s[ln] + red_s[64+ln] + red_s[128+ln] + red_s[192+ln];
    float ssq = red_q2[ln] + red_q2[64+ln] + red_q2[128+ln] + red_q2[192+ln];
    float mean = sum * 0.00390625f;
    float var  = ssq * 0.00390625f - mean*mean;
    float rstd = rsqrtf(var + 1e-5f);
    #pragma unroll
    for (int j = 0; j < 64; ++j){
      const int c = cbeg + j;
      sh_h[ln*LDH + c] = f2bf((vals[j] - mean) * rstd * ln1w[c] + ln1b[c]);
    }
  }
  __syncthreads();

  // ---- per-wave attention; wave wv owns heads 2wv, 2wv+1 ----
  const float scale = 0.1767766952966369f;  // 1/sqrt(32)
  f32x4 oacc[4][4];
  #pragma unroll
  for (int mt=0;mt<4;++mt)
    #pragma unroll
    for (int j=0;j<4;++j)
      oacc[mt][j] = (f32x4){0.f,0.f,0.f,0.f};

  #pragma unroll
  for (int hd = 0; hd < 2; ++hd){
    const int hc = (2*wv + hd) * 32;
    const int tq = (2*wv + hd) * 2;       // q tile base; k: +16; v: +32

    // ---- q + k fused (shared A-frags) ----
    {
      f32x4 aq[4][2], ak[4][2];
      #pragma unroll
      for (int mt=0;mt<4;++mt){
        aq[mt][0]=(f32x4){0,0,0,0}; aq[mt][1]=(f32x4){0,0,0,0};
        ak[mt][0]=(f32x4){0,0,0,0}; ak[mt][1]=(f32x4){0,0,0,0};
      }
      #pragma unroll
      for (int kt=0;kt<8;++kt){
        bf16x8 av[4], bq[2], bk[2];
        #pragma unroll
        for (int mt=0;mt<4;++mt)
          av[mt] = *(const bf16x8*)&sh_h[(mt*16+rowa)*LDH + kt*32 + kg*8];
        #pragma unroll
        for (int nt=0;nt<2;++nt){
          bq[nt] = WF(wqkv, tq + nt,      8, kt, ln);
          bk[nt] = WF(wqkv, 16 + tq + nt, 8, kt, ln);
        }
        #pragma unroll
        for (int mt=0;mt<4;++mt)
          #pragma unroll
          for (int nt=0;nt<2;++nt){
            aq[mt][nt] = __builtin_amdgcn_mfma_f32_16x16x32_bf16(av[mt], bq[nt], aq[mt][nt], 0, 0, 0);
            ak[mt][nt] = __builtin_amdgcn_mfma_f32_16x16x32_bf16(av[mt], bk[nt], ak[mt][nt], 0, 0, 0);
          }
      }
      #pragma unroll
      for (int nt=0;nt<2;++nt){
        const float biasq = inb[hc + nt*16 + rowa];
        const float biask = inb[256 + hc + nt*16 + rowa];
        #pragma unroll
        for (int mt=0;mt<4;++mt)
          #pragma unroll
          for (int i=0;i<4;++i){
            slotA[(mt*16 + kg*4 + i)*LDS_S + nt*16 + rowa] = f2bf(aq[mt][nt][i] + biasq);
            slotB[(mt*16 + kg*4 + i)*LDS_S + nt*16 + rowa] = f2bf(ak[mt][nt][i] + biask);
          }
      }
    }

    // ---- S = q @ k^T ----
    f32x4 sacc[4][4];
    #pragma unroll
    for (int mt=0;mt<4;++mt)
      #pragma unroll
      for (int nt=0;nt<4;++nt)
        sacc[mt][nt] = (f32x4){0.f,0.f,0.f,0.f};
    {
      bf16x8 aq[4], bk[4];
      #pragma unroll
      for (int mt=0;mt<4;++mt)
        aq[mt] = *(const bf16x8*)&slotA[(mt*16+rowa)*LDS_S + kg*8];
      #pragma unroll
      for (int nt=0;nt<4;++nt)
        bk[nt] = *(const bf16x8*)&slotB[(nt*16+rowa)*LDS_S + kg*8];
      __builtin_amdgcn_s_setprio(1);
      #pragma unroll
      for (int mt=0;mt<4;++mt)
        #pragma unroll
        for (int nt=0;nt<4;++nt)
          sacc[mt][nt] = __builtin_amdgcn_mfma_f32_16x16x32_bf16(aq[mt], bk[nt], sacc[mt][nt], 0, 0, 0);
      __builtin_amdgcn_s_setprio(0);
    }

    // ---- v -> vT [32][72] in slotB (k consumed; stride 72: no aliasing) ----
    {
      f32x4 accv[4][2];
      #pragma unroll
      for (int mt=0;mt<4;++mt){ accv[mt][0]=(f32x4){0,0,0,0}; accv[mt][1]=(f32x4){0,0,0,0}; }
      #pragma unroll
      for (int kt=0;kt<8;++kt){
        bf16x8 av[4], bw[2];
        #pragma unroll
        for (int mt=0;mt<4;++mt)
          av[mt] = *(const bf16x8*)&sh_h[(mt*16+rowa)*LDH + kt*32 + kg*8];
        #pragma unroll
        for (int nt=0;nt<2;++nt)
          bw[nt] = WF(wqkv, 32 + tq + nt, 8, kt, ln);
        #pragma unroll
        for (int mt=0;mt<4;++mt)
          #pragma unroll
          for (int nt=0;nt<2;++nt)
            accv[mt][nt] = __builtin_amdgcn_mfma_f32_16x16x32_bf16(av[mt], bw[nt], accv[mt][nt], 0, 0, 0);
      }
      #pragma unroll
      for (int nt=0;nt<2;++nt){
        const float bias = inb[512 + hc + nt*16 + rowa];
        #pragma unroll
        for (int mt=0;mt<4;++mt)
          #pragma unroll
          for (int i=0;i<4;++i)
            slotB[(nt*16 + rowa)*LDVT + mt*16 + kg*4 + i] = f2bf(accv[mt][nt][i] + bias);  // [ch][tok]
      }
    }

    // ---- softmax ----
    #pragma unroll
    for (int mt=0;mt<4;++mt){
      #pragma unroll
      for (int i=0;i<4;++i){
        float v0 = sacc[mt][0][i]*scale;
        float v1 = sacc[mt][1][i]*scale;
        float v2 = sacc[mt][2][i]*scale;
        float v3 = sacc[mt][3][i]*scale;
        float mx = fmaxf(fmaxf(v0,v1), fmaxf(v2,v3));
        #pragma unroll
        for (int d=1; d<16; d<<=1) mx = fmaxf(mx, __shfl_xor(mx, d, 64));
        v0 = __expf(v0-mx); v1 = __expf(v1-mx); v2 = __expf(v2-mx); v3 = __expf(v3-mx);
        float sm = v0+v1+v2+v3;
        #pragma unroll
        for (int d=1; d<16; d<<=1) sm += __shfl_xor(sm, d, 64);
        const float inv = 1.f / sm;
        sacc[mt][0][i] = v0*inv; sacc[mt][1][i] = v1*inv;
        sacc[mt][2][i] = v2*inv; sacc[mt][3][i] = v3*inv;
      }
    }

    // ---- PV in two kv-chunks of 32, P through slotA ----
    #pragma unroll
    for (int ck=0; ck<2; ++ck){
      #pragma unroll
      for (int ntl=0; ntl<2; ++ntl)
        #pragma unroll
        for (int mt=0;mt<4;++mt)
          #pragma unroll
          for (int i=0;i<4;++i)
            slotA[(mt*16 + kg*4 + i)*LDS_S + ntl*16 + rowa] = f2bf(sacc[mt][2*ck+ntl][i]);
      bf16x8 ap[4], bv[2];
      #pragma unroll
      for (int mt=0;mt<4;++mt)
        ap[mt] = *(const bf16x8*)&slotA[(mt*16+rowa)*LDS_S + kg*8];
      #pragma unroll
      for (int nt=0;nt<2;++nt)
        bv[nt] = *(const bf16x8*)&slotB[(nt*16+rowa)*LDVT + ck*32 + kg*8];
      __builtin_amdgcn_s_setprio(1);
      #pragma unroll
      for (int mt=0;mt<4;++mt)
        #pragma unroll
        for (int nt=0;nt<2;++nt)
          oacc[mt][hd*2+nt] = __builtin_amdgcn_mfma_f32_16x16x32_bf16(ap[mt], bv[nt], oacc[mt][hd*2+nt], 0, 0, 0);
      __builtin_amdgcn_s_setprio(0);
    }
  }

  __syncthreads();   // all waves done with h -> region becomes o

  #pragma unroll
  for (int j=0;j<4;++j){
    const int col = wv*64 + j*16 + rowa;
    #pragma unroll
    for (int mt=0;mt<4;++mt)
      #pragma unroll
      for (int i=0;i<4;++i)
        sh_h[(mt*16 + kg*4 + i)*LDH + col] = f2bf(oacc[mt][j][i]);
  }
  __syncthreads();

  // ---- out-proj SWAPPED: D'[ch][tok] = wout x o^T; + bias + x residual -> win2T ----
  {
    f32x4 acc[4][4];   // [c0(ch)][t0(tok)]
    #pragma unroll
    for (int c0=0;c0<4;++c0)
      #pragma unroll
      for (int t0=0;t0<4;++t0)
        acc[c0][t0] = (f32x4){0.f,0.f,0.f,0.f};
    for (int kt=0; kt<8; ++kt){
      bf16x8 aw[4], bo[4];
      #pragma unroll
      for (int c0=0;c0<4;++c0)
        aw[c0] = WF(wout, wv*4 + c0, 8, kt, ln);
      #pragma unroll
      for (int t0=0;t0<4;++t0)
        bo[t0] = *(const bf16x8*)&sh_h[(t0*16+rowa)*LDH + kt*32 + kg*8];
      #pragma unroll
      for (int c0=0;c0<4;++c0)
        #pragma unroll
        for (int t0=0;t0<4;++t0)
          acc[c0][t0] = __builtin_amdgcn_mfma_f32_16x16x32_bf16(aw[c0], bo[t0], acc[c0][t0], 0, 0, 0);
    }
    #pragma unroll
    for (int c0=0;c0<4;++c0){
      #pragma unroll
      for (int i=0;i<4;++i){
        const int ch = wv*64 + c0*16 + kg*4 + i;
        const float bias = outb[ch];
        #pragma unroll
        for (int t0=0;t0<4;++t0){
          const int tok = t0*16 + rowa;
          const int r = tok >> 3, cw = tok & 7;
          const int hh2 = (wh*8 + r + 4) & 127;
          const int wc2 = (ww*8 + cw + 4) & 127;
          const float res = x[xbase + (ch << 14) + hh2*128 + wc2];   // coalesced over rowa
          win2T[(wi<<14) + ch*64 + tok] = f2bf(acc[c0][t0][i] + bias + res);
        }
      }
    }
  }
}

// ---------------- kernel 2: LN2 + pipelined MLP (interleaved) + residual + scatter ----------------
#define K2_OFF_M   33792
#define K2_OFF_RED 51200
#define K2_SMEM    53248

__device__ __forceinline__ void g1_step(const short* __restrict__ w1, const short* Y,
                                        int chk, int kt, int wv, int rowa, int kg, int ln,
                                        f32x4 acc1[2][4]){
  bf16x8 aw[2], bh[4];
  #pragma unroll
  for (int rt=0;rt<2;++rt)
    aw[rt] = WF(w1, chk*8 + wv*2 + rt, 8, kt, ln);
  #pragma unroll
  for (int ct=0;ct<4;++ct)
    bh[ct] = *(const bf16x8*)&Y[(ct*16+rowa)*LDH + kt*32 + kg*8];
  #pragma unroll
  for (int rt=0;rt<2;++rt)
    #pragma unroll
    for (int ct=0;ct<4;++ct)
      acc1[rt][ct] = __builtin_amdgcn_mfma_f32_16x16x32_bf16(aw[rt], bh[ct], acc1[rt][ct], 0, 0, 0);
}

__device__ __forceinline__ void g2_step(const short* M, const short* __restrict__ w2,
                                        int chk, int kt2, int wv, int rowa, int kg, int ln,
                                        f32x4 acc2[4][4]){
  bf16x8 aw2[4], bm[4];
  #pragma unroll
  for (int c0=0;c0<4;++c0)
    aw2[c0] = WF(w2, wv*4 + c0, 32, chk*4 + kt2, ln);
  #pragma unroll
  for (int t0=0;t0<4;++t0)
    bm[t0] = *(const bf16x8*)&M[(t0*16+rowa)*LDM + kt2*32 + kg*8];
  #pragma unroll
  for (int c0=0;c0<4;++c0)
    #pragma unroll
    for (int t0=0;t0<4;++t0)
      acc2[c0][t0] = __builtin_amdgcn_mfma_f32_16x16x32_bf16(aw2[c0], bm[t0], acc2[c0][t0], 0, 0, 0);
}

__device__ __forceinline__ void mlp_gelu_store(short* M, const float* __restrict__ b1,
                                               int chk, int wv, int rowa, int kg,
                                               const f32x4 acc1[2][4]){
  #pragma unroll
  for (int rt=0;rt<2;++rt){
    const int hidb = wv*32 + rt*16 + kg*4;
    const f32x4 b1v = *(const f32x4*)&b1[chk*128 + hidb];
    #pragma unroll
    for (int ct=0;ct<4;++ct){
      bf16x4 st;
      #pragma unroll
      for (int i=0;i<4;++i)
        st[i] = f2bf(gelu_f(acc1[rt][ct][i] + b1v[i]));
      *(bf16x4*)&M[(ct*16 + rowa)*LDM + hidb] = st;
    }
  }
}

__global__ __launch_bounds__(256, 3)
void swin_mlp_kernel(const short* __restrict__ win2T,
                     const float* __restrict__ ln2w, const float* __restrict__ ln2b,
                     const float* __restrict__ b1,   const float* __restrict__ b2,
                     const short* __restrict__ w1,   const short* __restrict__ w2,
                     float* __restrict__ out)
{
  __shared__ char smem[K2_SMEM];
  short* Y = (short*)smem;
  short* M = (short*)(smem + K2_OFF_M);
  float* red_s  = (float*)(smem + K2_OFF_RED);
  float* red_q2 = red_s + 256;

  const int tid = threadIdx.x;
  const int wv  = tid >> 6;
  const int ln  = tid & 63;
  const int rowa = ln & 15;
  const int kg   = ln >> 4;
  const int wi = blockIdx.x;
  const int wb = wi << 14;   // win2T window base (256*64)

  // ---- LN2 from win2T (coalesced rows) ----
  {
    float vals[64];
    float s = 0.f, sq = 0.f;
    const int cbeg = wv*64;
    #pragma unroll
    for (int j=0;j<64;++j){
      float v = bf2f(win2T[wb + (cbeg + j)*64 + ln]);
      vals[j] = v; s += v; sq += v*v;
    }
    red_s[cbeg + ln]  = s;
    red_q2[cbeg + ln] = sq;
    __syncthreads();
    float sum = red_s[ln] + red_s[64+ln] + red_s[128+ln] + red_s[192+ln];
    float ssq = red_q2[ln] + red_q2[64+ln] + red_q2[128+ln] + red_q2[192+ln];
    float mean = sum * 0.00390625f;
    float var  = ssq * 0.00390625f - mean*mean;
    float rstd = rsqrtf(var + 1e-5f);
    #pragma unroll
    for (int q=0;q<8;++q){
      bf16x8 pk;
      #pragma unroll
      for (int e=0;e<8;++e){
        const int c = cbeg + q*8 + e;
        pk[e] = f2bf((vals[q*8+e] - mean) * rstd * ln2w[c] + ln2b[c]);
      }
      *(bf16x8*)&Y[ln*LDH + cbeg + q*8] = pk;
    }
  }
  __syncthreads();

  // ---- pipelined MLP, kt-interleaved: G1(c+1) steps woven with G2(c) steps ----
  f32x4 acc2[4][4];
  #pragma unroll
  for (int c0=0;c0<4;++c0)
    #pragma unroll
    for (int t0=0;t0<4;++t0)
      acc2[c0][t0] = (f32x4){0.f,0.f,0.f,0.f};

  // prologue: chunk 0 -> M
  {
    f32x4 acc1[2][4];
    #pragma unroll
    for (int rt=0;rt<2;++rt)
      #pragma unroll
      for (int ct=0;ct<4;++ct)
        acc1[rt][ct] = (f32x4){0.f,0.f,0.f,0.f};
    #pragma unroll
    for (int kt=0;kt<8;++kt) g1_step(w1, Y, 0, kt, wv, rowa, kg, ln, acc1);
    mlp_gelu_store(M, b1, 0, wv, rowa, kg, acc1);
  }
  __syncthreads();   // M(0) ready

  #pragma unroll
  for (int c = 0; c < 8; ++c){
    if (c < 7){
      f32x4 acc1n[2][4];
      #pragma unroll
      for (int rt=0;rt<2;++rt)
        #pragma unroll
        for (int ct=0;ct<4;++ct)
          acc1n[rt][ct] = (f32x4){0.f,0.f,0.f,0.f};
      #pragma unroll
      for (int kt=0;kt<4;++kt){
        g1_step(w1, Y, c+1, kt, wv, rowa, kg, ln, acc1n);
        g2_step(M, w2, c, kt, wv, rowa, kg, ln, acc2);
      }
      #pragma unroll
      for (int kt=4;kt<8;++kt)
        g1_step(w1, Y, c+1, kt, wv, rowa, kg, ln, acc1n);
      __syncthreads();   // all M(c) reads done
      mlp_gelu_store(M, b1, c+1, wv, rowa, kg, acc1n);
      __syncthreads();   // M(c+1) ready
    } else {
      #pragma unroll
      for (int kt=0;kt<4;++kt)
        g2_step(M, w2, c, kt, wv, rowa, kg, ln, acc2);
    }
  }

  // ---- epilogue: D'[ch][tok]: + b2 + win2T residual (coalesced), coalesced NCHW store ----
  const int b  = wi >> 8;
  const int wh = (wi >> 4) & 15;
  const int ww = wi & 15;
  #pragma unroll
  for (int c0=0;c0<4;++c0){
    #pragma unroll
    for (int i=0;i<4;++i){
      const int ch = wv*64 + c0*16 + kg*4 + i;
      const float bias = b2[ch];
      #pragma unroll
      for (int t0=0;t0<4;++t0){
        const int tok = t0*16 + rowa;
        float v = acc2[c0][t0][i] + bias + bf2f(win2T[wb + ch*64 + tok]);
        const int r = tok >> 3, cw = tok & 7;
        const int hh = (wh*8 + r + 4) & 127;
        const int wcc = (ww*8 + cw + 4) & 127;
        out[(((b<<8) + ch) << 14) + hh*128 + wcc] = v;
      }
    }
  }
}

// ---------------- launch ----------------
extern "C" void kernel_launch(void* const* d_in, const int* in_sizes, int n_in,
                              void* d_out, int out_size, void* d_ws, size_t ws_size,
                              hipStream_t stream) {
  (void)in_sizes; (void)n_in; (void)out_size; (void)ws_size;
  const float* x    = (const float*)d_in[0];
  const float* ln1w = (const float*)d_in[1];
  const float* ln1b = (const float*)d_in[2];
  const float* inw  = (const float*)d_in[3];
  const float* inb  = (const float*)d_in[4];
  const float* outw = (const float*)d_in[5];
  const float* outb = (const float*)d_in[6];
  const float* ln2w = (const float*)d_in[7];
  const float* ln2b = (const float*)d_in[8];
  const float* w1f  = (const float*)d_in[9];
  const float* b1   = (const float*)d_in[10];
  const float* w2f  = (const float*)d_in[11];
  const float* b2   = (const float*)d_in[12];
  float* out = (float*)d_out;

  short* ws    = (short*)d_ws;
  short* wqkv  = ws;            // 768*256   (frag-packed, KT=8)
  short* wout  = ws + 196608;   // 256*256   (frag-packed, KT=8)
  short* w1b   = ws + 262144;   // 1024*256  (frag-packed, KT=8)
  short* w2b   = ws + 524288;   // 256*1024  (frag-packed, KT=32)
  short* win2T = ws + 786432;   // 2048 x 256ch x 64tok bf16 (transposed)

  hipLaunchKernelGGL(wpack_kernel, dim3(96),  dim3(256), 0, stream, inw,  wqkv, 256);
  hipLaunchKernelGGL(wpack_kernel, dim3(32),  dim3(256), 0, stream, outw, wout, 256);
  hipLaunchKernelGGL(wpack_kernel, dim3(128), dim3(256), 0, stream, w1f,  w1b,  256);
  hipLaunchKernelGGL(wpack_kernel, dim3(128), dim3(256), 0, stream, w2f,  w2b,  1024);

  hipLaunchKernelGGL(swin_attn_kernel, dim3(2048), dim3(256), 0, stream,
                     x, ln1w, ln1b, inb, outb, wqkv, wout, win2T);
  hipLaunchKernelGGL(swin_mlp_kernel, dim3(2048), dim3(256), 0, stream,
                     win2T, ln2w, ln2b, b1, b2, w1b, w2b, out);
}

// Round 9
// 538.423 us; speedup vs baseline: 1.5684x; 1.2636x over previous
//
#include <hip/hip_runtime.h>
#include <math.h>

// Swin block: B=8, C=256, H=W=128, WS=8, SS=4, NH=8, dh=32
// Split kernels; weights repacked into MFMA-fragment order:
//   wf[((tile*KT + kt)*64 + lane)*8 + e] = W[tile*16 + (lane&15)][kt*32 + (lane>>4)*8 + e]
// attn: x read ONCE (bf16 stash in regs -> LDS bounce for residual); XCD-swizzled blocks.

#define LDH 264   // bf16 row stride for [64][256] tiles
#define LDS_S 40  // bf16 row stride for per-wave q/k slots [64][40]
#define LDVT 72   // bf16 row stride for vT [32][72] (>=64: no aliasing)
#define LDM 136   // bf16 row stride for m chunk [64][128]

typedef __attribute__((ext_vector_type(8))) short bf16x8;
typedef __attribute__((ext_vector_type(4))) short bf16x4;
typedef __attribute__((ext_vector_type(4))) float f32x4;

#define WF(wf, tile, KT, kt, ln) (*(const bf16x8*)&(wf)[((((tile)*(KT)) + (kt))*64 + (ln))*8])

static __device__ __forceinline__ float bf2f(short s){
  union { unsigned u; float f; } cv;
  cv.u = ((unsigned)(unsigned short)s) << 16;
  return cv.f;
}
static __device__ __forceinline__ short f2bf(float f){
  union { float f; unsigned u; } cv; cv.f = f;
  unsigned r = (cv.u + 0x7FFFu + ((cv.u >> 16) & 1u)) >> 16;  // RNE
  return (short)r;
}
static __device__ __forceinline__ float gelu_f(float x){
  return 0.5f * x * (1.0f + erff(x * 0.7071067811865475f));
}

// ---------------- K0: fp32 -> bf16 fragment-order repack ----------------
__global__ void wpack_kernel(const float* __restrict__ src, short* __restrict__ dst,
                             int K){
  const int t8 = blockIdx.x * 256 + threadIdx.x;   // one thread per 8 elements
  const int e0 = t8 * 8;
  const int l   = (e0 >> 3) & 63;
  const int blk = e0 >> 9;          // tile*KT + kt
  const int KT  = K >> 5;
  const int kt   = blk % KT;
  const int tile = blk / KT;
  const int row = tile*16 + (l & 15);
  const int kb  = kt*32 + (l >> 4)*8;
  const float* s = src + row*K + kb;
  bf16x8 o;
  #pragma unroll
  for (int e=0;e<8;++e) o[e] = f2bf(s[e]);
  *(bf16x8*)&dst[e0] = o;
}

// ---------------- kernel 1: LN1 + QKV + attention + out-proj(swapped) -> win2T ----------------
#define K1_OFF_WV  33792
#define K1_OFF_RED 74752
#define K1_SMEM    76800

__global__ __launch_bounds__(256, 2)
void swin_attn_kernel(const float* __restrict__ x,
                      const float* __restrict__ ln1w, const float* __restrict__ ln1b,
                      const float* __restrict__ inb,  const float* __restrict__ outb,
                      const short* __restrict__ wqkv, const short* __restrict__ wout,
                      short* __restrict__ win2T)
{
  __shared__ char smem[K1_SMEM];
  short* sh_h   = (short*)smem;
  short* xsh    = (short*)(smem + K1_OFF_WV);   // x bf16 stash [64][264] (post-attention)
  float* red_s  = (float*)(smem + K1_OFF_RED);
  float* red_q2 = red_s + 256;

  const int tid = threadIdx.x;
  const int wv  = tid >> 6;
  const int ln  = tid & 63;
  const int rowa = ln & 15;
  const int kg   = ln >> 4;

  short* slotA = (short*)(smem + K1_OFF_WV) + wv*5120;  // [64][40]
  short* slotB = slotA + 2560;                          // k[64][40] -> vT[32][72]

  // XCD-aware swizzle: 8 XCDs x 256 consecutive windows (2048 % 8 == 0 -> bijective)
  const int bid = blockIdx.x;
  const int wi  = ((bid & 7) << 8) | (bid >> 3);
  const int b  = wi >> 8;
  const int wh = (wi >> 4) & 15;
  const int ww = wi & 15;

  const int hh = (wh*8 + (ln >> 3) + 4) & 127;   // roll(-4)
  const int wc = (ww*8 + (ln & 7) + 4) & 127;
  const int offhw = hh*128 + wc;
  const int xbase = b << 22;

  // ---- LN1 (values in regs); pack raw x as bf16 for the residual (carried in 32 regs) ----
  unsigned xpk[32];
  {
    const int cbeg = wv*64;
    float vals[64];
    float s = 0.f, sq = 0.f;
    #pragma unroll
    for (int j = 0; j < 64; ++j){
      float v = x[xbase + ((cbeg + j) << 14) + offhw];
      vals[j] = v; s += v; sq += v*v;
    }
    #pragma unroll
    for (int p = 0; p < 32; ++p){
      const unsigned lo = (unsigned)(unsigned short)f2bf(vals[2*p]);
      const unsigned hi = (unsigned)(unsigned short)f2bf(vals[2*p+1]);
      xpk[p] = lo | (hi << 16);
    }
    red_s[cbeg + ln]  = s;
    red_q2[cbeg + ln] = sq;
    __syncthreads();
    float sum = red_s[ln] + red_s[64+ln] + red_s[128+ln] + red_s[192+ln];
    float ssq = red_q2[ln] + red_q2[64+ln] + red_q2[128+ln] + red_q2[192+ln];
    float mean = sum * 0.00390625f;
    float var  = ssq * 0.00390625f - mean*mean;
    float rstd = rsqrtf(var + 1e-5f);
    #pragma unroll
    for (int j = 0; j < 64; ++j){
      const int c = cbeg + j;
      sh_h[ln*LDH + c] = f2bf((vals[j] - mean) * rstd * ln1w[c] + ln1b[c]);
    }
  }
  __syncthreads();

  // ---- per-wave attention; wave wv owns heads 2wv, 2wv+1 ----
  const float scale = 0.1767766952966369f;  // 1/sqrt(32)
  f32x4 oacc[4][4];
  #pragma unroll
  for (int mt=0;mt<4;++mt)
    #pragma unroll
    for (int j=0;j<4;++j)
      oacc[mt][j] = (f32x4){0.f,0.f,0.f,0.f};

  #pragma unroll
  for (int hd = 0; hd < 2; ++hd){
    const int hc = (2*wv + hd) * 32;
    const int tq = (2*wv + hd) * 2;       // q tile base; k: +16; v: +32

    // ---- q + k fused (shared A-frags) ----
    {
      f32x4 aq[4][2], ak[4][2];
      #pragma unroll
      for (int mt=0;mt<4;++mt){
        aq[mt][0]=(f32x4){0,0,0,0}; aq[mt][1]=(f32x4){0,0,0,0};
        ak[mt][0]=(f32x4){0,0,0,0}; ak[mt][1]=(f32x4){0,0,0,0};
      }
      #pragma unroll
      for (int kt=0;kt<8;++kt){
        bf16x8 av[4], bq[2], bk[2];
        #pragma unroll
        for (int mt=0;mt<4;++mt)
          av[mt] = *(const bf16x8*)&sh_h[(mt*16+rowa)*LDH + kt*32 + kg*8];
        #pragma unroll
        for (int nt=0;nt<2;++nt){
          bq[nt] = WF(wqkv, tq + nt,      8, kt, ln);
          bk[nt] = WF(wqkv, 16 + tq + nt, 8, kt, ln);
        }
        #pragma unroll
        for (int mt=0;mt<4;++mt)
          #pragma unroll
          for (int nt=0;nt<2;++nt){
            aq[mt][nt] = __builtin_amdgcn_mfma_f32_16x16x32_bf16(av[mt], bq[nt], aq[mt][nt], 0, 0, 0);
            ak[mt][nt] = __builtin_amdgcn_mfma_f32_16x16x32_bf16(av[mt], bk[nt], ak[mt][nt], 0, 0, 0);
          }
      }
      #pragma unroll
      for (int nt=0;nt<2;++nt){
        const float biasq = inb[hc + nt*16 + rowa];
        const float biask = inb[256 + hc + nt*16 + rowa];
        #pragma unroll
        for (int mt=0;mt<4;++mt)
          #pragma unroll
          for (int i=0;i<4;++i){
            slotA[(mt*16 + kg*4 + i)*LDS_S + nt*16 + rowa] = f2bf(aq[mt][nt][i] + biasq);
            slotB[(mt*16 + kg*4 + i)*LDS_S + nt*16 + rowa] = f2bf(ak[mt][nt][i] + biask);
          }
      }
    }

    // ---- S = q @ k^T ----
    f32x4 sacc[4][4];
    #pragma unroll
    for (int mt=0;mt<4;++mt)
      #pragma unroll
      for (int nt=0;nt<4;++nt)
        sacc[mt][nt] = (f32x4){0.f,0.f,0.f,0.f};
    {
      bf16x8 aq[4], bk[4];
      #pragma unroll
      for (int mt=0;mt<4;++mt)
        aq[mt] = *(const bf16x8*)&slotA[(mt*16+rowa)*LDS_S + kg*8];
      #pragma unroll
      for (int nt=0;nt<4;++nt)
        bk[nt] = *(const bf16x8*)&slotB[(nt*16+rowa)*LDS_S + kg*8];
      __builtin_amdgcn_s_setprio(1);
      #pragma unroll
      for (int mt=0;mt<4;++mt)
        #pragma unroll
        for (int nt=0;nt<4;++nt)
          sacc[mt][nt] = __builtin_amdgcn_mfma_f32_16x16x32_bf16(aq[mt], bk[nt], sacc[mt][nt], 0, 0, 0);
      __builtin_amdgcn_s_setprio(0);
    }

    // ---- v -> vT [32][72] in slotB (k consumed; stride 72: no aliasing) ----
    {
      f32x4 accv[4][2];
      #pragma unroll
      for (int mt=0;mt<4;++mt){ accv[mt][0]=(f32x4){0,0,0,0}; accv[mt][1]=(f32x4){0,0,0,0}; }
      #pragma unroll
      for (int kt=0;kt<8;++kt){
        bf16x8 av[4], bw[2];
        #pragma unroll
        for (int mt=0;mt<4;++mt)
          av[mt] = *(const bf16x8*)&sh_h[(mt*16+rowa)*LDH + kt*32 + kg*8];
        #pragma unroll
        for (int nt=0;nt<2;++nt)
          bw[nt] = WF(wqkv, 32 + tq + nt, 8, kt, ln);
        #pragma unroll
        for (int mt=0;mt<4;++mt)
          #pragma unroll
          for (int nt=0;nt<2;++nt)
            accv[mt][nt] = __builtin_amdgcn_mfma_f32_16x16x32_bf16(av[mt], bw[nt], accv[mt][nt], 0, 0, 0);
      }
      #pragma unroll
      for (int nt=0;nt<2;++nt){
        const float bias = inb[512 + hc + nt*16 + rowa];
        #pragma unroll
        for (int mt=0;mt<4;++mt)
          #pragma unroll
          for (int i=0;i<4;++i)
            slotB[(nt*16 + rowa)*LDVT + mt*16 + kg*4 + i] = f2bf(accv[mt][nt][i] + bias);  // [ch][tok]
      }
    }

    // ---- softmax ----
    #pragma unroll
    for (int mt=0;mt<4;++mt){
      #pragma unroll
      for (int i=0;i<4;++i){
        float v0 = sacc[mt][0][i]*scale;
        float v1 = sacc[mt][1][i]*scale;
        float v2 = sacc[mt][2][i]*scale;
        float v3 = sacc[mt][3][i]*scale;
        float mx = fmaxf(fmaxf(v0,v1), fmaxf(v2,v3));
        #pragma unroll
        for (int d=1; d<16; d<<=1) mx = fmaxf(mx, __shfl_xor(mx, d, 64));
        v0 = __expf(v0-mx); v1 = __expf(v1-mx); v2 = __expf(v2-mx); v3 = __expf(v3-mx);
        float sm = v0+v1+v2+v3;
        #pragma unroll
        for (int d=1; d<16; d<<=1) sm += __shfl_xor(sm, d, 64);
        const float inv = 1.f / sm;
        sacc[mt][0][i] = v0*inv; sacc[mt][1][i] = v1*inv;
        sacc[mt][2][i] = v2*inv; sacc[mt][3][i] = v3*inv;
      }
    }

    // ---- PV in two kv-chunks of 32, P through slotA ----
    #pragma unroll
    for (int ck=0; ck<2; ++ck){
      #pragma unroll
      for (int ntl=0; ntl<2; ++ntl)
        #pragma unroll
        for (int mt=0;mt<4;++mt)
          #pragma unroll
          for (int i=0;i<4;++i)
            slotA[(mt*16 + kg*4 + i)*LDS_S + ntl*16 + rowa] = f2bf(sacc[mt][2*ck+ntl][i]);
      bf16x8 ap[4], bv[2];
      #pragma unroll
      for (int mt=0;mt<4;++mt)
        ap[mt] = *(const bf16x8*)&slotA[(mt*16+rowa)*LDS_S + kg*8];
      #pragma unroll
      for (int nt=0;nt<2;++nt)
        bv[nt] = *(const bf16x8*)&slotB[(nt*16+rowa)*LDVT + ck*32 + kg*8];
      __builtin_amdgcn_s_setprio(1);
      #pragma unroll
      for (int mt=0;mt<4;++mt)
        #pragma unroll
        for (int nt=0;nt<2;++nt)
          oacc[mt][hd*2+nt] = __builtin_amdgcn_mfma_f32_16x16x32_bf16(ap[mt], bv[nt], oacc[mt][hd*2+nt], 0, 0, 0);
      __builtin_amdgcn_s_setprio(0);
    }
  }

  __syncthreads();   // all waves done with h & slots -> sh becomes o, slots become xsh

  // o -> sh; x stash -> xsh (slots region, now dead)
  #pragma unroll
  for (int j=0;j<4;++j){
    const int col = wv*64 + j*16 + rowa;
    #pragma unroll
    for (int mt=0;mt<4;++mt)
      #pragma unroll
      for (int i=0;i<4;++i)
        sh_h[(mt*16 + kg*4 + i)*LDH + col] = f2bf(oacc[mt][j][i]);
  }
  {
    const int cbeg = wv*64;
    #pragma unroll
    for (int q=0;q<8;++q){
      bf16x8 pk;
      #pragma unroll
      for (int e=0;e<4;++e){
        const unsigned w = xpk[q*4+e];
        pk[2*e]   = (short)(w & 0xffffu);
        pk[2*e+1] = (short)(w >> 16);
      }
      *(bf16x8*)&xsh[ln*LDH + cbeg + q*8] = pk;
    }
  }
  __syncthreads();

  // ---- out-proj SWAPPED: D'[ch][tok] = wout x o^T; + bias + x residual(LDS) -> win2T ----
  {
    f32x4 acc[4][4];   // [c0(ch)][t0(tok)]
    #pragma unroll
    for (int c0=0;c0<4;++c0)
      #pragma unroll
      for (int t0=0;t0<4;++t0)
        acc[c0][t0] = (f32x4){0.f,0.f,0.f,0.f};
    for (int kt=0; kt<8; ++kt){
      bf16x8 aw[4], bo[4];
      #pragma unroll
      for (int c0=0;c0<4;++c0)
        aw[c0] = WF(wout, wv*4 + c0, 8, kt, ln);
      #pragma unroll
      for (int t0=0;t0<4;++t0)
        bo[t0] = *(const bf16x8*)&sh_h[(t0*16+rowa)*LDH + kt*32 + kg*8];
      #pragma unroll
      for (int c0=0;c0<4;++c0)
        #pragma unroll
        for (int t0=0;t0<4;++t0)
          acc[c0][t0] = __builtin_amdgcn_mfma_f32_16x16x32_bf16(aw[c0], bo[t0], acc[c0][t0], 0, 0, 0);
    }
    #pragma unroll
    for (int c0=0;c0<4;++c0){
      #pragma unroll
      for (int i=0;i<4;++i){
        const int ch = wv*64 + c0*16 + kg*4 + i;
        const float bias = outb[ch];
        #pragma unroll
        for (int t0=0;t0<4;++t0){
          const int tok = t0*16 + rowa;
          const float res = bf2f(xsh[tok*LDH + ch]);
          win2T[(wi<<14) + ch*64 + tok] = f2bf(acc[c0][t0][i] + bias + res);
        }
      }
    }
  }
}

// ---------------- kernel 2: LN2 + pipelined MLP (interleaved) + residual + scatter ----------------
#define K2_OFF_M   33792
#define K2_OFF_RED 51200
#define K2_SMEM    53248

__device__ __forceinline__ void g1_step(const short* __restrict__ w1, const short* Y,
                                        int chk, int kt, int wv, int rowa, int kg, int ln,
                                        f32x4 acc1[2][4]){
  bf16x8 aw[2], bh[4];
  #pragma unroll
  for (int rt=0;rt<2;++rt)
    aw[rt] = WF(w1, chk*8 + wv*2 + rt, 8, kt, ln);
  #pragma unroll
  for (int ct=0;ct<4;++ct)
    bh[ct] = *(const bf16x8*)&Y[(ct*16+rowa)*LDH + kt*32 + kg*8];
  #pragma unroll
  for (int rt=0;rt<2;++rt)
    #pragma unroll
    for (int ct=0;ct<4;++ct)
      acc1[rt][ct] = __builtin_amdgcn_mfma_f32_16x16x32_bf16(aw[rt], bh[ct], acc1[rt][ct], 0, 0, 0);
}

__device__ __forceinline__ void g2_step(const short* M, const short* __restrict__ w2,
                                        int chk, int kt2, int wv, int rowa, int kg, int ln,
                                        f32x4 acc2[4][4]){
  bf16x8 aw2[4], bm[4];
  #pragma unroll
  for (int c0=0;c0<4;++c0)
    aw2[c0] = WF(w2, wv*4 + c0, 32, chk*4 + kt2, ln);
  #pragma unroll
  for (int t0=0;t0<4;++t0)
    bm[t0] = *(const bf16x8*)&M[(t0*16+rowa)*LDM + kt2*32 + kg*8];
  #pragma unroll
  for (int c0=0;c0<4;++c0)
    #pragma unroll
    for (int t0=0;t0<4;++t0)
      acc2[c0][t0] = __builtin_amdgcn_mfma_f32_16x16x32_bf16(aw2[c0], bm[t0], acc2[c0][t0], 0, 0, 0);
}

__device__ __forceinline__ void mlp_gelu_store(short* M, const float* __restrict__ b1,
                                               int chk, int wv, int rowa, int kg,
                                               const f32x4 acc1[2][4]){
  #pragma unroll
  for (int rt=0;rt<2;++rt){
    const int hidb = wv*32 + rt*16 + kg*4;
    const f32x4 b1v = *(const f32x4*)&b1[chk*128 + hidb];
    #pragma unroll
    for (int ct=0;ct<4;++ct){
      bf16x4 st;
      #pragma unroll
      for (int i=0;i<4;++i)
        st[i] = f2bf(gelu_f(acc1[rt][ct][i] + b1v[i]));
      *(bf16x4*)&M[(ct*16 + rowa)*LDM + hidb] = st;
    }
  }
}

__global__ __launch_bounds__(256, 3)
void swin_mlp_kernel(const short* __restrict__ win2T,
                     const float* __restrict__ ln2w, const float* __restrict__ ln2b,
                     const float* __restrict__ b1,   const float* __restrict__ b2,
                     const short* __restrict__ w1,   const short* __restrict__ w2,
                     float* __restrict__ out)
{
  __shared__ char smem[K2_SMEM];
  short* Y = (short*)smem;
  short* M = (short*)(smem + K2_OFF_M);
  float* red_s  = (float*)(smem + K2_OFF_RED);
  float* red_q2 = red_s + 256;

  const int tid = threadIdx.x;
  const int wv  = tid >> 6;
  const int ln  = tid & 63;
  const int rowa = ln & 15;
  const int kg   = ln >> 4;
  const int wi = blockIdx.x;
  const int wb = wi << 14;   // win2T window base (256*64)

  // ---- LN2 from win2T (coalesced rows) ----
  {
    float vals[64];
    float s = 0.f, sq = 0.f;
    const int cbeg = wv*64;
    #pragma unroll
    for (int j=0;j<64;++j){
      float v = bf2f(win2T[wb + (cbeg + j)*64 + ln]);
      vals[j] = v; s += v; sq += v*v;
    }
    red_s[cbeg + ln]  = s;
    red_q2[cbeg + ln] = sq;
    __syncthreads();
    float sum = red_s[ln] + red_s[64+ln] + red_s[128+ln] + red_s[192+ln];
    float ssq = red_q2[ln] + red_q2[64+ln] + red_q2[128+ln] + red_q2[192+ln];
    float mean = sum * 0.00390625f;
    float var  = ssq * 0.00390625f - mean*mean;
    float rstd = rsqrtf(var + 1e-5f);
    #pragma unroll
    for (int q=0;q<8;++q){
      bf16x8 pk;
      #pragma unroll
      for (int e=0;e<8;++e){
        const int c = cbeg + q*8 + e;
        pk[e] = f2bf((vals[q*8+e] - mean) * rstd * ln2w[c] + ln2b[c]);
      }
      *(bf16x8*)&Y[ln*LDH + cbeg + q*8] = pk;
    }
  }
  __syncthreads();

  // ---- pipelined MLP, kt-interleaved: G1(c+1) steps woven with G2(c) steps ----
  f32x4 acc2[4][4];
  #pragma unroll
  for (int c0=0;c0<4;++c0)
    #pragma unroll
    for (int t0=0;t0<4;++t0)
      acc2[c0][t0] = (f32x4){0.f,0.f,0.f,0.f};

  // prologue: chunk 0 -> M
  {
    f32x4 acc1[2][4];
    #pragma unroll
    for (int rt=0;rt<2;++rt)
      #pragma unroll
      for (int ct=0;ct<4;++ct)
        acc1[rt][ct] = (f32x4){0.f,0.f,0.f,0.f};
    #pragma unroll
    for (int kt=0;kt<8;++kt) g1_step(w1, Y, 0, kt, wv, rowa, kg, ln, acc1);
    mlp_gelu_store(M, b1, 0, wv, rowa, kg, acc1);
  }
  __syncthreads();   // M(0) ready

  #pragma unroll
  for (int c = 0; c < 8; ++c){
    if (c < 7){
      f32x4 acc1n[2][4];
      #pragma unroll
      for (int rt=0;rt<2;++rt)
        #pragma unroll
        for (int ct=0;ct<4;++ct)
          acc1n[rt][ct] = (f32x4){0.f,0.f,0.f,0.f};
      #pragma unroll
      for (int kt=0;kt<4;++kt){
        g1_step(w1, Y, c+1, kt, wv, rowa, kg, ln, acc1n);
        g2_step(M, w2, c, kt, wv, rowa, kg, ln, acc2);
      }
      #pragma unroll
      for (int kt=4;kt<8;++kt)
        g1_step(w1, Y, c+1, kt, wv, rowa, kg, ln, acc1n);
      __syncthreads();   // all M(c) reads done
      mlp_gelu_store(M, b1, c+1, wv, rowa, kg, acc1n);
      __syncthreads();   // M(c+1) ready
    } else {
      #pragma unroll
      for (int kt=0;kt<4;++kt)
        g2_step(M, w2, c, kt, wv, rowa, kg, ln, acc2);
    }
  }

  // ---- epilogue: D'[ch][tok]: + b2 + win2T residual (coalesced), coalesced NCHW store ----
  const int b  = wi >> 8;
  const int wh = (wi >> 4) & 15;
  const int ww = wi & 15;
  #pragma unroll
  for (int c0=0;c0<4;++c0){
    #pragma unroll
    for (int i=0;i<4;++i){
      const int ch = wv*64 + c0*16 + kg*4 + i;
      const float bias = b2[ch];
      #pragma unroll
      for (int t0=0;t0<4;++t0){
        const int tok = t0*16 + rowa;
        float v = acc2[c0][t0][i] + bias + bf2f(win2T[wb + ch*64 + tok]);
        const int r = tok >> 3, cw = tok & 7;
        const int hh = (wh*8 + r + 4) & 127;
        const int wcc = (ww*8 + cw + 4) & 127;
        out[(((b<<8) + ch) << 14) + hh*128 + wcc] = v;
      }
    }
  }
}

// ---------------- launch ----------------
extern "C" void kernel_launch(void* const* d_in, const int* in_sizes, int n_in,
                              void* d_out, int out_size, void* d_ws, size_t ws_size,
                              hipStream_t stream) {
  (void)in_sizes; (void)n_in; (void)out_size; (void)ws_size;
  const float* x    = (const float*)d_in[0];
  const float* ln1w = (const float*)d_in[1];
  const float* ln1b = (const float*)d_in[2];
  const float* inw  = (const float*)d_in[3];
  const float* inb  = (const float*)d_in[4];
  const float* outw = (const float*)d_in[5];
  const float* outb = (const float*)d_in[6];
  const float* ln2w = (const float*)d_in[7];
  const float* ln2b = (const float*)d_in[8];
  const float* w1f  = (const float*)d_in[9];
  const float* b1   = (const float*)d_in[10];
  const float* w2f  = (const float*)d_in[11];
  const float* b2   = (const float*)d_in[12];
  float* out = (float*)d_out;

  short* ws    = (short*)d_ws;
  short* wqkv  = ws;            // 768*256   (frag-packed, KT=8)
  short* wout  = ws + 196608;   // 256*256   (frag-packed, KT=8)
  short* w1b   = ws + 262144;   // 1024*256  (frag-packed, KT=8)
  short* w2b   = ws + 524288;   // 256*1024  (frag-packed, KT=32)
  short* win2T = ws + 786432;   // 2048 x 256ch x 64tok bf16 (transposed)

  hipLaunchKernelGGL(wpack_kernel, dim3(96),  dim3(256), 0, stream, inw,  wqkv, 256);
  hipLaunchKernelGGL(wpack_kernel, dim3(32),  dim3(256), 0, stream, outw, wout, 256);
  hipLaunchKernelGGL(wpack_kernel, dim3(128), dim3(256), 0, stream, w1f,  w1b,  256);
  hipLaunchKernelGGL(wpack_kernel, dim3(128), dim3(256), 0, stream, w2f,  w2b,  1024);

  hipLaunchKernelGGL(swin_attn_kernel, dim3(2048), dim3(256), 0, stream,
                     x, ln1w, ln1b, inb, outb, wqkv, wout, win2T);
  hipLaunchKernelGGL(swin_mlp_kernel, dim3(2048), dim3(256), 0, stream,
                     win2T, ln2w, ln2b, b1, b2, w1b, w2b, out);
}